// Round 1
// baseline (302.699 us; speedup 1.0000x reference)
//
#include <hip/hip_runtime.h>
#include <math.h>

#define HW 16384          // 128*128
#define NMIX 10
#define NPIX (32 * HW)    // B*H*W = 524288

__device__ __forceinline__ float fexp(float x) { return __expf(x); }
__device__ __forceinline__ float flog(float x) { return __logf(x); }
__device__ __forceinline__ float frcp(float x) { return __builtin_amdgcn_rcpf(x); }

// tanh(y) = sign(y) * (1 - t) / (1 + t), t = exp(-2|y|)
__device__ __forceinline__ float ftanh(float y) {
    float t = fexp(-2.0f * fabsf(y));
    float r = (1.0f - t) * frcp(1.0f + t);
    return (y >= 0.0f) ? r : -r;
}

// discretized-logistic per-channel log prob, matching reference semantics
__device__ __forceinline__ float channel_logprob(float x, float mean, float ls) {
    const float INV255 = 0.00392156862745098f;   // 1/255
    const float LOG127_5 = 4.852030263919617f;   // log(127.5)
    float inv = fexp(-ls);
    float centered = x - mean;
    float plus_in = inv * (centered + INV255);
    float min_in  = inv * (centered - INV255);
    float mid_in  = inv * centered;

    // shared exp(-|x|) feeds both sigmoid and softplus (stable for |x| up to ~2200)
    float tp = fexp(-fabsf(plus_in));
    float rp = frcp(1.0f + tp);
    float sp_plus  = fmaxf(plus_in, 0.0f) + flog(1.0f + tp);
    float sig_plus = (plus_in >= 0.0f) ? rp : tp * rp;

    float tm = fexp(-fabsf(min_in));
    float rm = frcp(1.0f + tm);
    float sp_min  = fmaxf(min_in, 0.0f) + flog(1.0f + tm);
    float sig_min = (min_in >= 0.0f) ? rm : tm * rm;

    float tmid = fexp(-fabsf(mid_in));
    float sp_mid = fmaxf(mid_in, 0.0f) + flog(1.0f + tmid);

    float log_cdf_plus    = plus_in - sp_plus;
    float log_om_cdf_min  = -sp_min;
    float cdf_delta       = sig_plus - sig_min;
    float log_pdf_mid     = mid_in - ls - 2.0f * sp_mid;

    float inner = (cdf_delta > 1e-5f) ? flog(fmaxf(cdf_delta, 1e-12f))
                                      : (log_pdf_mid - LOG127_5);
    return (x < -0.999f) ? log_cdf_plus
         : ((x > 0.999f) ? log_om_cdf_min : inner);
}

__global__ __launch_bounds__(256) void pixelcnn_kernel(
    const float* __restrict__ samples, const float* __restrict__ params,
    float* __restrict__ out)
{
    int p  = blockIdx.x * blockDim.x + threadIdx.x;   // pixel index
    int b  = p >> 14;          // / HW
    int hw = p & (HW - 1);     // % HW

    const float* sp = samples + (size_t)b * 3   * HW + hw;
    const float* pp = params  + (size_t)b * 100 * HW + hw;

    float x0 = 2.0f * sp[0]              - 1.0f;
    float x1 = 2.0f * sp[(size_t)HW]     - 1.0f;
    float x2 = 2.0f * sp[(size_t)2 * HW] - 1.0f;

    // online logsumexp state: raw mixture scores and logit normalizer
    float mr = -3.4e38f, sr = 0.0f;
    float ml = -3.4e38f, sl = 0.0f;

    #pragma unroll 2
    for (int k = 0; k < NMIX; ++k) {
        float logit = pp[(size_t)(k)      * HW];
        float mean0 = pp[(size_t)(10 + k) * HW];
        float lsc0  = pp[(size_t)(20 + k) * HW];
        float cw0   = pp[(size_t)(30 + k) * HW];
        float mean1 = pp[(size_t)(40 + k) * HW];
        float lsc1  = pp[(size_t)(50 + k) * HW];
        float cw1   = pp[(size_t)(60 + k) * HW];
        float mean2 = pp[(size_t)(70 + k) * HW];
        float lsc2  = pp[(size_t)(80 + k) * HW];
        float cw2   = pp[(size_t)(90 + k) * HW];

        float ls0 = fmaxf(lsc0, -7.0f);
        float ls1 = fmaxf(lsc1, -7.0f);
        float ls2 = fmaxf(lsc2, -7.0f);
        float c0 = ftanh(cw0);
        float c1 = ftanh(cw1);
        float c2 = ftanh(cw2);

        float m1 = mean0;
        float m2 = mean1 + c0 * x0;
        float m3 = mean2 + c1 * x0 + c2 * x1;

        float lp = channel_logprob(x0, m1, ls0)
                 + channel_logprob(x1, m2, ls1)
                 + channel_logprob(x2, m3, ls2);
        float raw = lp + logit;

        // online LSE update (exp of -huge underflows to 0 safely)
        float nm = fmaxf(mr, raw);
        sr = sr * fexp(mr - nm) + fexp(raw - nm);
        mr = nm;
        float nl = fmaxf(ml, logit);
        sl = sl * fexp(ml - nl) + fexp(logit - nl);
        ml = nl;
    }

    float val = (mr + flog(sr)) - (ml + flog(sl));

    // block reduction: 64-lane wave shuffle, then LDS across 4 waves
    #pragma unroll
    for (int off = 32; off > 0; off >>= 1)
        val += __shfl_down(val, off, 64);

    __shared__ float wsum[4];
    int lane = threadIdx.x & 63;
    int wid  = threadIdx.x >> 6;
    if (lane == 0) wsum[wid] = val;
    __syncthreads();
    if (threadIdx.x == 0) {
        float bsum = (wsum[0] + wsum[1]) + (wsum[2] + wsum[3]);
        atomicAdd(out, bsum);
    }
}

extern "C" void kernel_launch(void* const* d_in, const int* in_sizes, int n_in,
                              void* d_out, int out_size, void* d_ws, size_t ws_size,
                              hipStream_t stream) {
    const float* samples = (const float*)d_in[0];
    const float* params  = (const float*)d_in[1];
    float* out = (float*)d_out;

    hipMemsetAsync(out, 0, sizeof(float), stream);   // d_out is poisoned each launch
    pixelcnn_kernel<<<NPIX / 256, 256, 0, stream>>>(samples, params, out);
}

// Round 2
// 295.768 us; speedup vs baseline: 1.0234x; 1.0234x over previous
//
#include <hip/hip_runtime.h>
#include <math.h>

#define HW 16384            // 128*128
#define HW4 4096            // HW / 4 (float4 units per plane)
#define NMIX 10
#define NPIX (32 * HW)      // B*H*W = 524288
#define NQUAD (NPIX / 4)    // 131072 float4-pixel groups

__device__ __forceinline__ float fexp(float x) { return __expf(x); }
__device__ __forceinline__ float flog(float x) { return __logf(x); }
__device__ __forceinline__ float frcp(float x) { return __builtin_amdgcn_rcpf(x); }

// tanh(y) = sign(y) * (1 - t) / (1 + t), t = exp(-2|y|)
__device__ __forceinline__ float ftanh(float y) {
    float t = fexp(-2.0f * fabsf(y));
    float r = (1.0f - t) * frcp(1.0f + t);
    return (y >= 0.0f) ? r : -r;
}

// discretized-logistic per-channel log prob, matching reference semantics
__device__ __forceinline__ float channel_logprob(float x, float mean, float ls) {
    const float INV255 = 0.00392156862745098f;   // 1/255
    const float LOG127_5 = 4.852030263919617f;   // log(127.5)
    float inv = fexp(-ls);
    float centered = x - mean;
    float plus_in = inv * (centered + INV255);
    float min_in  = inv * (centered - INV255);
    float mid_in  = inv * centered;

    // shared exp(-|x|) feeds both sigmoid and softplus (stable everywhere)
    float tp = fexp(-fabsf(plus_in));
    float rp = frcp(1.0f + tp);
    float sp_plus  = fmaxf(plus_in, 0.0f) + flog(1.0f + tp);
    float sig_plus = (plus_in >= 0.0f) ? rp : tp * rp;

    float tm = fexp(-fabsf(min_in));
    float rm = frcp(1.0f + tm);
    float sp_min  = fmaxf(min_in, 0.0f) + flog(1.0f + tm);
    float sig_min = (min_in >= 0.0f) ? rm : tm * rm;

    float tmid = fexp(-fabsf(mid_in));
    float sp_mid = fmaxf(mid_in, 0.0f) + flog(1.0f + tmid);

    float log_cdf_plus    = plus_in - sp_plus;
    float log_om_cdf_min  = -sp_min;
    float cdf_delta       = sig_plus - sig_min;
    float log_pdf_mid     = mid_in - ls - 2.0f * sp_mid;

    float inner = (cdf_delta > 1e-5f) ? flog(fmaxf(cdf_delta, 1e-12f))
                                      : (log_pdf_mid - LOG127_5);
    return (x < -0.999f) ? log_cdf_plus
         : ((x > 0.999f) ? log_om_cdf_min : inner);
}

__global__ __launch_bounds__(256) void pixelcnn_kernel(
    const float4* __restrict__ samples, const float4* __restrict__ params,
    float* __restrict__ out)
{
    int q  = blockIdx.x * blockDim.x + threadIdx.x;   // float4-pixel-group index
    int b  = q >> 12;            // / HW4
    int hw = q & (HW4 - 1);      // % HW4

    const float4* sp = samples + (size_t)b * 3   * HW4 + hw;
    const float4* pp = params  + (size_t)b * 100 * HW4 + hw;

    float4 s0 = sp[0];
    float4 s1 = sp[HW4];
    float4 s2 = sp[2 * HW4];
    const float* fs0 = (const float*)&s0;
    const float* fs1 = (const float*)&s1;
    const float* fs2 = (const float*)&s2;

    float x0[4], x1[4], x2[4], mr[4], sr[4], ml[4], sl[4];
    #pragma unroll
    for (int j = 0; j < 4; ++j) {
        x0[j] = 2.0f * fs0[j] - 1.0f;
        x1[j] = 2.0f * fs1[j] - 1.0f;
        x2[j] = 2.0f * fs2[j] - 1.0f;
        mr[j] = -3.4e38f; sr[j] = 0.0f;
        ml[j] = -3.4e38f; sl[j] = 0.0f;
    }

    #pragma unroll 1
    for (int k = 0; k < NMIX; ++k) {
        float4 vlogit = pp[(size_t)(k)      * HW4];
        float4 vmean0 = pp[(size_t)(10 + k) * HW4];
        float4 vlsc0  = pp[(size_t)(20 + k) * HW4];
        float4 vcw0   = pp[(size_t)(30 + k) * HW4];
        float4 vmean1 = pp[(size_t)(40 + k) * HW4];
        float4 vlsc1  = pp[(size_t)(50 + k) * HW4];
        float4 vcw1   = pp[(size_t)(60 + k) * HW4];
        float4 vmean2 = pp[(size_t)(70 + k) * HW4];
        float4 vlsc2  = pp[(size_t)(80 + k) * HW4];
        float4 vcw2   = pp[(size_t)(90 + k) * HW4];
        const float* logit = (const float*)&vlogit;
        const float* mean0 = (const float*)&vmean0;
        const float* lsc0  = (const float*)&vlsc0;
        const float* cw0   = (const float*)&vcw0;
        const float* mean1 = (const float*)&vmean1;
        const float* lsc1  = (const float*)&vlsc1;
        const float* cw1   = (const float*)&vcw1;
        const float* mean2 = (const float*)&vmean2;
        const float* lsc2  = (const float*)&vlsc2;
        const float* cw2   = (const float*)&vcw2;

        #pragma unroll
        for (int j = 0; j < 4; ++j) {
            float ls0 = fmaxf(lsc0[j], -7.0f);
            float ls1 = fmaxf(lsc1[j], -7.0f);
            float ls2 = fmaxf(lsc2[j], -7.0f);
            float c0 = ftanh(cw0[j]);
            float c1 = ftanh(cw1[j]);
            float c2 = ftanh(cw2[j]);

            float m1 = mean0[j];
            float m2 = mean1[j] + c0 * x0[j];
            float m3 = mean2[j] + c1 * x0[j] + c2 * x1[j];

            float lp = channel_logprob(x0[j], m1, ls0)
                     + channel_logprob(x1[j], m2, ls1)
                     + channel_logprob(x2[j], m3, ls2);
            float raw = lp + logit[j];

            // online LSE update (exp of -huge underflows to 0 safely)
            float nm = fmaxf(mr[j], raw);
            sr[j] = sr[j] * fexp(mr[j] - nm) + fexp(raw - nm);
            mr[j] = nm;
            float nl = fmaxf(ml[j], logit[j]);
            sl[j] = sl[j] * fexp(ml[j] - nl) + fexp(logit[j] - nl);
            ml[j] = nl;
        }
    }

    float val = 0.0f;
    #pragma unroll
    for (int j = 0; j < 4; ++j)
        val += (mr[j] + flog(sr[j])) - (ml[j] + flog(sl[j]));

    // block reduction: 64-lane wave shuffle, then LDS across 4 waves
    #pragma unroll
    for (int off = 32; off > 0; off >>= 1)
        val += __shfl_down(val, off, 64);

    __shared__ float wsum[4];
    int lane = threadIdx.x & 63;
    int wid  = threadIdx.x >> 6;
    if (lane == 0) wsum[wid] = val;
    __syncthreads();
    if (threadIdx.x == 0) {
        float bsum = (wsum[0] + wsum[1]) + (wsum[2] + wsum[3]);
        atomicAdd(out, bsum);
    }
}

extern "C" void kernel_launch(void* const* d_in, const int* in_sizes, int n_in,
                              void* d_out, int out_size, void* d_ws, size_t ws_size,
                              hipStream_t stream) {
    const float4* samples = (const float4*)d_in[0];
    const float4* params  = (const float4*)d_in[1];
    float* out = (float*)d_out;

    hipMemsetAsync(out, 0, sizeof(float), stream);   // d_out is poisoned each launch
    pixelcnn_kernel<<<NQUAD / 256, 256, 0, stream>>>(samples, params, out);
}

// Round 3
// 295.162 us; speedup vs baseline: 1.0255x; 1.0021x over previous
//
#include <hip/hip_runtime.h>
#include <math.h>

#define HW 16384            // 128*128
#define HW2 8192            // HW / 2 (float2 units per plane)
#define NMIX 10
#define NPIX (32 * HW)      // B*H*W = 524288
#define NTHREADS (NPIX / 2) // 262144 threads, 2 pixels each
#define NBLOCKS (NTHREADS / 256)

__device__ __forceinline__ float fexp(float x) { return __expf(x); }
__device__ __forceinline__ float flog(float x) { return __logf(x); }
__device__ __forceinline__ float frcp(float x) { return __builtin_amdgcn_rcpf(x); }

// tanh(y) = sign(y) * (1 - t) / (1 + t), t = exp(-2|y|)
__device__ __forceinline__ float ftanh(float y) {
    float t = fexp(-2.0f * fabsf(y));
    float r = (1.0f - t) * frcp(1.0f + t);
    return (y >= 0.0f) ? r : -r;
}

// discretized-logistic per-channel log prob.
// waveEdge is wave-uniform: whether ANY lane in this wave has |x|>0.999.
__device__ __forceinline__ float channel_logprob(float x, float mean, float ls,
                                                 bool waveEdge) {
    const float INV255 = 0.00392156862745098f;   // 1/255
    const float LOG127_5 = 4.852030263919617f;   // log(127.5)
    float inv = fexp(-ls);
    float centered = x - mean;
    float plus_in = inv * (centered + INV255);
    float min_in  = inv * (centered - INV255);
    float mid_in  = inv * centered;

    float tp = fexp(-fabsf(plus_in));
    float rp = frcp(1.0f + tp);
    float sig_plus = (plus_in >= 0.0f) ? rp : tp * rp;

    float tm = fexp(-fabsf(min_in));
    float rm = frcp(1.0f + tm);
    float sig_min = (min_in >= 0.0f) ? rm : tm * rm;

    float cdf_delta = sig_plus - sig_min;

    float tmid = fexp(-fabsf(mid_in));
    float sp_mid = fmaxf(mid_in, 0.0f) + flog(1.0f + tmid);
    float log_pdf_mid = mid_in - ls - 2.0f * sp_mid;

    float r = (cdf_delta > 1e-5f) ? flog(fmaxf(cdf_delta, 1e-12f))
                                  : (log_pdf_mid - LOG127_5);
    if (waveEdge) {   // wave-uniform branch: only pay for edge waves
        float sp_plus = fmaxf(plus_in, 0.0f) + flog(1.0f + tp);
        float sp_min  = fmaxf(min_in, 0.0f) + flog(1.0f + tm);
        float log_cdf_plus   = plus_in - sp_plus;
        float log_om_cdf_min = -sp_min;
        r = (x < -0.999f) ? log_cdf_plus
          : ((x > 0.999f) ? log_om_cdf_min : r);
    }
    return r;
}

// online LSE update with ONE exp: if new <= m: s += exp(new-m);
// else: s = s*exp(m-new) + 1, m = new.
__device__ __forceinline__ void lse_update(float& m, float& s, float v) {
    float d = v - m;
    float e = fexp(-fabsf(d));
    bool grow = (d > 0.0f);
    s = grow ? (s * e + 1.0f) : (s + e);
    m = grow ? v : m;
}

__global__ __launch_bounds__(256, 4) void pixelcnn_kernel(
    const float2* __restrict__ samples, const float2* __restrict__ params,
    float* __restrict__ out)
{
    int q  = blockIdx.x * blockDim.x + threadIdx.x;   // float2-pixel-pair index
    int b  = q >> 13;            // / HW2
    int hw = q & (HW2 - 1);      // % HW2

    const float2* sp = samples + (size_t)b * 3   * HW2 + hw;
    const float2* pp = params  + (size_t)b * 100 * HW2 + hw;

    float2 s0 = sp[0];
    float2 s1 = sp[HW2];
    float2 s2 = sp[2 * HW2];

    float x0[2] = {2.0f * s0.x - 1.0f, 2.0f * s0.y - 1.0f};
    float x1[2] = {2.0f * s1.x - 1.0f, 2.0f * s1.y - 1.0f};
    float x2[2] = {2.0f * s2.x - 1.0f, 2.0f * s2.y - 1.0f};

    bool edge = false;
    #pragma unroll
    for (int j = 0; j < 2; ++j)
        edge |= (fabsf(x0[j]) > 0.999f) | (fabsf(x1[j]) > 0.999f)
              | (fabsf(x2[j]) > 0.999f);
    bool waveEdge = (__ballot(edge) != 0ULL);   // wave-uniform

    float mr[2] = {-3.4e38f, -3.4e38f}, sr[2] = {0.0f, 0.0f};
    float ml[2] = {-3.4e38f, -3.4e38f}, sl[2] = {0.0f, 0.0f};

    // fields f=0..9 live at plane (10*f + k): logit,mean0,lsc0,cw0,mean1,lsc1,cw1,mean2,lsc2,cw2
    float2 cur[10], nxt[10];
    #pragma unroll
    for (int f = 0; f < 10; ++f) cur[f] = pp[(size_t)(10 * f) * HW2];

    #pragma unroll 1
    for (int k = 0; k < NMIX; ++k) {
        // prefetch next mixture's planes; loads stay in flight during compute
        int kn = (k < NMIX - 1) ? k + 1 : k;
        #pragma unroll
        for (int f = 0; f < 10; ++f) nxt[f] = pp[(size_t)(10 * f + kn) * HW2];

        const float* logit = (const float*)&cur[0];
        const float* mean0 = (const float*)&cur[1];
        const float* lsc0  = (const float*)&cur[2];
        const float* cw0   = (const float*)&cur[3];
        const float* mean1 = (const float*)&cur[4];
        const float* lsc1  = (const float*)&cur[5];
        const float* cw1   = (const float*)&cur[6];
        const float* mean2 = (const float*)&cur[7];
        const float* lsc2  = (const float*)&cur[8];
        const float* cw2   = (const float*)&cur[9];

        #pragma unroll
        for (int j = 0; j < 2; ++j) {
            float ls0 = fmaxf(lsc0[j], -7.0f);
            float ls1 = fmaxf(lsc1[j], -7.0f);
            float ls2 = fmaxf(lsc2[j], -7.0f);
            float c0 = ftanh(cw0[j]);
            float c1 = ftanh(cw1[j]);
            float c2 = ftanh(cw2[j]);

            float m1 = mean0[j];
            float m2 = mean1[j] + c0 * x0[j];
            float m3 = mean2[j] + c1 * x0[j] + c2 * x1[j];

            float lp = channel_logprob(x0[j], m1, ls0, waveEdge)
                     + channel_logprob(x1[j], m2, ls1, waveEdge)
                     + channel_logprob(x2[j], m3, ls2, waveEdge);

            lse_update(mr[j], sr[j], lp + logit[j]);
            lse_update(ml[j], sl[j], logit[j]);
        }

        #pragma unroll
        for (int f = 0; f < 10; ++f) cur[f] = nxt[f];
    }

    float val = 0.0f;
    #pragma unroll
    for (int j = 0; j < 2; ++j)
        val += (mr[j] + flog(sr[j])) - (ml[j] + flog(sl[j]));

    // block reduction: 64-lane wave shuffle, then LDS across 4 waves
    #pragma unroll
    for (int off = 32; off > 0; off >>= 1)
        val += __shfl_down(val, off, 64);

    __shared__ float wsum[4];
    int lane = threadIdx.x & 63;
    int wid  = threadIdx.x >> 6;
    if (lane == 0) wsum[wid] = val;
    __syncthreads();
    if (threadIdx.x == 0) {
        float bsum = (wsum[0] + wsum[1]) + (wsum[2] + wsum[3]);
        atomicAdd(out, bsum);
    }
}

extern "C" void kernel_launch(void* const* d_in, const int* in_sizes, int n_in,
                              void* d_out, int out_size, void* d_ws, size_t ws_size,
                              hipStream_t stream) {
    const float2* samples = (const float2*)d_in[0];
    const float2* params  = (const float2*)d_in[1];
    float* out = (float*)d_out;

    hipMemsetAsync(out, 0, sizeof(float), stream);   // d_out is poisoned each launch
    pixelcnn_kernel<<<NBLOCKS, 256, 0, stream>>>(samples, params, out);
}